// Round 4
// baseline (272.872 us; speedup 1.0000x reference)
//
#include <hip/hip_runtime.h>

// Problem constants (fixed by reference: B=64, T=1024, D=256)
constexpr int Bn = 64;
constexpr int Tn = 1024;
constexpr int Dn = 256;

constexpr int TPB   = 64;          // ONE wave per block: no barriers, no LDS
constexpr int QUADS = 4;           // 2x2 quadrants of the 64x64 cross matrix
constexpr int NBLK  = Tn * QUADS;  // 4096 blocks; 16 blocks/CU, 4 waves/SIMD
constexpr int NBIN  = 64;          // partial-sum bins (contention: 64 blocks/bin)

using short8 = __attribute__((ext_vector_type(8))) short;   // 8 bf16 — MFMA A/B frag
using f32x16 = __attribute__((ext_vector_type(16))) float;  // MFMA 32x32 accumulator

__device__ __forceinline__ float dot4(const float4& a, const float4& b) {
    return a.x * b.x + a.y * b.y + a.z * b.z + a.w * b.w;
}

// fp32 -> bf16 bits, round-to-nearest-even
__device__ __forceinline__ unsigned int bfbits(float x) {
    unsigned int u = __builtin_bit_cast(unsigned int, x);
    return (u + 0x7FFFu + ((u >> 16) & 1u)) >> 16;
}
__device__ __forceinline__ unsigned int pack_bf2(float lo, float hi) {
    return bfbits(lo) | (bfbits(hi) << 16);
}

__global__ __launch_bounds__(TPB, 4)   // cap 128 VGPR -> 4 waves/SIMD (16 wave-blocks/CU)
void cmfm_main(const float* __restrict__ fv, const float* __restrict__ fa,
               const int* __restrict__ labels, float* __restrict__ acc)
{
    const int lane = threadIdx.x;          // single wave
    const int bid  = blockIdx.x;

    // Bijective XCD swizzle (T1; 4096 % 8 == 0): the 4 quadrants of each t land on
    // the SAME XCD so the 2x logical read amplification is absorbed by that XCD's L2.
    const int lid  = (bid & 7) * (NBLK / 8) + (bid >> 3);
    const int t    = lid >> 2;
    const int quad = lid & 3;
    const int i0   = (quad >> 1) * 32;     // V-row block (C rows)
    const int j0   = (quad & 1) * 32;      // A-row block (C cols)
    const int mrow = lane & 31;
    const int half = lane >> 5;
    const bool diag = (i0 == j0);

    // MFMA frag source rows, direct from global: lane -> row (i0+mrow / j0+mrow),
    // k-slice 8*half within each K=16 step. Layout verified by rounds 1-3 (passed).
    const float* __restrict__ vrow = fv + ((size_t)(i0 + mrow) * Tn + t) * Dn + 8 * half;
    const float* __restrict__ arow = fa + ((size_t)(j0 + mrow) * Tn + t) * Dn + 8 * half;

    f32x16 C;
    #pragma unroll
    for (int r = 0; r < 16; ++r) C[r] = 0.f;

    float sqv = 0.f, sqa = 0.f, dva = 0.f;

    // 16 K-steps cover D=256. Straight-line, barrier-free: compiler pipelines loads.
    #pragma unroll
    for (int s = 0; s < 16; ++s) {
        const float4 v0 = *reinterpret_cast<const float4*>(vrow + 16 * s);
        const float4 v1 = *reinterpret_cast<const float4*>(vrow + 16 * s + 4);
        const float4 a0 = *reinterpret_cast<const float4*>(arow + 16 * s);
        const float4 a1 = *reinterpret_cast<const float4*>(arow + 16 * s + 4);

        sqv += dot4(v0, v0) + dot4(v1, v1);          // fp32 norms, exact
        sqa += dot4(a0, a0) + dot4(a1, a1);
        if (diag) dva += dot4(v0, a0) + dot4(v1, a1);  // aligned-pair dot (wave-uniform branch)

        union { short8 s8; uint4 u4; } av, bv;       // RNE bf16 pack for MFMA
        av.u4.x = pack_bf2(v0.x, v0.y); av.u4.y = pack_bf2(v0.z, v0.w);
        av.u4.z = pack_bf2(v1.x, v1.y); av.u4.w = pack_bf2(v1.z, v1.w);
        bv.u4.x = pack_bf2(a0.x, a0.y); bv.u4.y = pack_bf2(a0.z, a0.w);
        bv.u4.z = pack_bf2(a1.x, a1.y); bv.u4.w = pack_bf2(a1.z, a1.w);

        C = __builtin_amdgcn_mfma_f32_32x32x16_bf16(av.s8, bv.s8, C, 0, 0, 0);
    }

    // Row norms: halves hold disjoint k-subsets -> one cross-half combine.
    sqv += __shfl_xor(sqv, 32);
    sqa += __shfl_xor(sqa, 32);
    const float rv = 1.f / fmaxf(sqrtf(sqv), 1e-8f);   // row i0+mrow
    const float ra = 1.f / fmaxf(sqrtf(sqa), 1e-8f);   // row j0+mrow

    // Aligned-pair term: diagonal quadrants only (each row counted once per t).
    float pos = 0.f, neg = 0.f;
    if (diag) {
        dva += __shfl_xor(dva, 32);
        const float cosd = dva * rv * ra;
        const int lab = labels[i0 + mrow];
        if (half == 0) {                       // one lane per row
            if (lab == 0) pos = 1.f - cosd;    // d_bt = 1 - cos
            else          neg = cosd;          // (1 - d_bt) = cos
        }
    }

    // Cross term: scale by rv_i * ra_j, drop diagonal.
    // C/D mapping (m74/m101): col = lane&31, row = (reg&3) + 8*(reg>>2) + 4*(lane>>5)
    float od = 0.f;
    #pragma unroll
    for (int r = 0; r < 16; ++r) {
        const int ri = (r & 3) + 8 * (r >> 2) + 4 * half;
        const float rvi = __shfl(rv, ri);      // rv of row i0+ri lives on lane ri
        float c = C[r];
        if (diag && ri == mrow) c = 0.f;       // i == j diagonal
        od += rvi * ra * c;
    }

    // Wave reduce + 3 atomics into this block's bin.
    #pragma unroll
    for (int off = 1; off < 64; off <<= 1) {
        pos += __shfl_xor(pos, off);
        neg += __shfl_xor(neg, off);
        od  += __shfl_xor(od, off);
    }
    if (lane == 0) {
        float* bin = acc + (size_t)(bid & (NBIN - 1)) * 4;
        atomicAdd(bin + 0, pos);
        atomicAdd(bin + 1, neg);
        atomicAdd(bin + 2, od);
    }
}

__global__ void cmfm_final(const int* __restrict__ labels, const float* __restrict__ acc,
                           float* __restrict__ out) {
    const int l = threadIdx.x;     // 64 threads = 64 bins = 64 labels
    float p = acc[l * 4 + 0];
    float n = acc[l * 4 + 1];
    float o = acc[l * 4 + 2];
    float npf = (labels[l] == 0) ? 1.f : 0.f;
    #pragma unroll
    for (int off = 1; off < 64; off <<= 1) {
        p += __shfl_xor(p, off);
        n += __shfl_xor(n, off);
        o += __shfl_xor(o, off);
        npf += __shfl_xor(npf, off);
    }
    if (l == 0) {
        const int np = (int)(npf + 0.5f);
        const float cnt_pos = (float)np * (float)Tn;
        const float cnt_neg = (float)(Bn - np) * (float)Tn + (float)Bn * (float)(Bn - 1);
        float loss = 0.f;
        if (np > 0) loss += 2.0f * p / cnt_pos;                      // ALPHA
        loss += (2.0f * n + 1.0f * o / (float)Tn) / cnt_neg;         // BETA, GAMMA
        out[0] = loss;
    }
}

extern "C" void kernel_launch(void* const* d_in, const int* in_sizes, int n_in,
                              void* d_out, int out_size, void* d_ws, size_t ws_size,
                              hipStream_t stream) {
    const float* fv     = (const float*)d_in[0];
    const float* fa     = (const float*)d_in[1];
    const int*   labels = (const int*)d_in[2];
    float* acc = (float*)d_ws;        // 64 bins x {pos, neg, cross, pad}
    float* out = (float*)d_out;

    hipMemsetAsync(acc, 0, NBIN * 4 * sizeof(float), stream);
    cmfm_main<<<NBLK, TPB, 0, stream>>>(fv, fa, labels, acc);
    cmfm_final<<<1, 64, 0, stream>>>(labels, acc, out);
}

// Round 5
// 153.459 us; speedup vs baseline: 1.7781x; 1.7781x over previous
//
#include <hip/hip_runtime.h>

// Problem constants (fixed by reference: B=64, T=1024, D=256)
constexpr int Bn = 64;
constexpr int Tn = 1024;
constexpr int Dn = 256;

constexpr int TPB  = 256;       // 4 waves
constexpr int NBLK = Tn;        // one timestep per block; 4 blocks/CU, all resident
constexpr int CH   = 32;        // K per chunk
constexpr int NCH  = Dn / CH;   // 8 chunks
constexpr int NBIN = 64;        // partial-sum bins

using short8 = __attribute__((ext_vector_type(8))) short;   // 8 bf16 — MFMA A/B frag
using f32x16 = __attribute__((ext_vector_type(16))) float;  // MFMA 32x32 accumulator

__device__ __forceinline__ float dot4(const float4& a, const float4& b) {
    return a.x * b.x + a.y * b.y + a.z * b.z + a.w * b.w;
}

// fp32 -> bf16 bits, round-to-nearest-even
__device__ __forceinline__ unsigned int bfbits(float x) {
    unsigned int u = __builtin_bit_cast(unsigned int, x);
    return (u + 0x7FFFu + ((u >> 16) & 1u)) >> 16;
}
__device__ __forceinline__ unsigned int pack_bf2(float lo, float hi) {
    return bfbits(lo) | (bfbits(hi) << 16);
}

// Direct global->LDS 16B copy: prefetch depth lives in the vmcnt queue, costs 0 VGPRs.
__device__ __forceinline__ void gload16(const float* g, float* l) {
    __builtin_amdgcn_global_load_lds(
        (const __attribute__((address_space(1))) void*)g,
        (__attribute__((address_space(3))) void*)l,
        16, 0, 0);
}

// Barrier with COUNTED vmcnt (T4): chunk c's 4 loads retired, later chunks stay in flight.
// sched_barrier(0) per rule #18 (LDS reads have no compiler-visible dep on the HW LDS writes).
#define VM_BARRIER(N) do {                                      \
    asm volatile("s_waitcnt vmcnt(" #N ")" ::: "memory");       \
    __builtin_amdgcn_sched_barrier(0);                          \
    __builtin_amdgcn_s_barrier();                               \
    __builtin_amdgcn_sched_barrier(0);                          \
} while (0)

// All waves' ds ops retired (reads of the buffer we are about to overwrite / rvs writes).
#define RD_BARRIER() do {                                       \
    asm volatile("s_waitcnt lgkmcnt(0)" ::: "memory");          \
    __builtin_amdgcn_sched_barrier(0);                          \
    __builtin_amdgcn_s_barrier();                               \
    __builtin_amdgcn_sched_barrier(0);                          \
} while (0)

__global__ __launch_bounds__(TPB, 4)   // cap 128 VGPR -> 4 blocks/CU (16 waves/CU)
void cmfm_main(const float* __restrict__ fv, const float* __restrict__ fa,
               const int* __restrict__ labels, float* __restrict__ acc)
{
    // fp32 chunk staging, double-buffered: 64 rows x 32 floats = 8 KB per array per buf.
    // LDS layout linear for global_load_lds; swizzle via inverse-permuted GLOBAL source
    // (rule #21): LDS[row][pslot] holds global 16B slot (pslot ^ (row&7)).
    __shared__ __align__(16) float Vb[2][Bn * CH];
    __shared__ __align__(16) float Ab[2][Bn * CH];
    __shared__ float rvs[Bn], ras[Bn];
    __shared__ float wred[3][TPB / 64];

    const int tid  = threadIdx.x;
    const int lane = tid & 63;
    const int wave = tid >> 6;
    const int t    = blockIdx.x;

    // MFMA geometry: 4 waves -> 2x2 quadrants of the 64x64 cross matrix
    const int i0   = (wave >> 1) * 32;
    const int j0   = (wave & 1) * 32;
    const int mrow = lane & 31;
    const int half = lane >> 5;
    const bool diag = (i0 == j0);      // waves 0 and 3 own the norm accumulation

    const int rV = i0 + mrow;          // V fragment row for this lane
    const int rA = j0 + mrow;          // A fragment row
    const unsigned vbase = (unsigned)rV * CH;   // float index of row base in a chunk
    const unsigned abase = (unsigned)rA * CH;
    const int kV = rV & 7;             // read swizzle keys
    const int kA = rA & 7;

    // Staging map: thread stages LDS bytes [tid*16 + n*4096] (linear, as HW requires).
    // row = n*32 + (tid>>3); pslot = tid&7; global slot = pslot ^ (row&7).
    const int sr0 = (tid >> 3);                    // row within 32-row group
    const int su0 = (tid & 7);                     // physical slot

    f32x16 C;
    #pragma unroll
    for (int r = 0; r < 16; ++r) C[r] = 0.f;

    float sqv = 0.f, sqa = 0.f, dva = 0.f;

    #define STAGE(c, b) do {                                                        \
        _Pragma("unroll")                                                           \
        for (int n = 0; n < 2; ++n) {                                               \
            const int r  = n * 32 + sr0;                                            \
            const int u  = su0 ^ (r & 7);                                           \
            const size_t goff = ((size_t)r * Tn + t) * Dn + (c) * CH + u * 4;       \
            gload16(fv + goff, &Vb[b][n * 1024 + tid * 4]);                         \
            gload16(fa + goff, &Ab[b][n * 1024 + tid * 4]);                         \
        }                                                                           \
    } while (0)

    STAGE(0, 0);                       // prologue: 2 chunks in flight (8 vmem instrs)
    STAGE(1, 1);

    #pragma unroll
    for (int c = 0; c < NCH; ++c) {
        const int b = c & 1;
        if (c < NCH - 1) { VM_BARRIER(4); }   // chunk c landed; chunk c+1 stays in flight
        else            { VM_BARRIER(0); }

        // consume chunk c: 2 K=16 steps
        #pragma unroll
        for (int s = 0; s < 2; ++s) {
            const int us = 4 * s + 2 * half;   // logical 16B slot of this lane's k-slice
            const float4 v0 = *reinterpret_cast<const float4*>(&Vb[b][vbase + (((us    ) ^ kV) << 2)]);
            const float4 v1 = *reinterpret_cast<const float4*>(&Vb[b][vbase + (((us + 1) ^ kV) << 2)]);
            const float4 a0 = *reinterpret_cast<const float4*>(&Ab[b][abase + (((us    ) ^ kA) << 2)]);
            const float4 a1 = *reinterpret_cast<const float4*>(&Ab[b][abase + (((us + 1) ^ kA) << 2)]);

            if (diag) {                        // each (row,k) hits exactly one diag-wave lane
                sqv += dot4(v0, v0) + dot4(v1, v1);
                sqa += dot4(a0, a0) + dot4(a1, a1);
                dva += dot4(v0, a0) + dot4(v1, a1);
            }

            union { short8 s8; uint4 u4; } av, bv;   // RNE bf16 pack for MFMA
            av.u4.x = pack_bf2(v0.x, v0.y); av.u4.y = pack_bf2(v0.z, v0.w);
            av.u4.z = pack_bf2(v1.x, v1.y); av.u4.w = pack_bf2(v1.z, v1.w);
            bv.u4.x = pack_bf2(a0.x, a0.y); bv.u4.y = pack_bf2(a0.z, a0.w);
            bv.u4.z = pack_bf2(a1.x, a1.y); bv.u4.w = pack_bf2(a1.z, a1.w);
            C = __builtin_amdgcn_mfma_f32_32x32x16_bf16(av.s8, bv.s8, C, 0, 0, 0);
        }

        RD_BARRIER();                          // all waves done reading buf b
        if (c + 2 < NCH) STAGE(c + 2, b);      // overwrite it with chunk c+2
    }
    #undef STAGE

    // ---- norms (diag waves): halves hold disjoint k-subsets -> one combine ----
    float pos = 0.f, neg = 0.f;
    if (diag) {
        sqv += __shfl_xor(sqv, 32);
        sqa += __shfl_xor(sqa, 32);
        dva += __shfl_xor(dva, 32);
        const float rv = 1.f / fmaxf(sqrtf(sqv), 1e-8f);
        const float ra = 1.f / fmaxf(sqrtf(sqa), 1e-8f);
        if (half == 0) {
            rvs[rV] = rv;                      // wave0 covers rows 0-31, wave3 rows 32-63
            ras[rV] = ra;
            const float cosd = dva * rv * ra;  // aligned-pair cosine (exact fp32)
            if (labels[rV] == 0) pos = 1.f - cosd;   // d_bt = 1 - cos
            else                 neg = cosd;          // (1 - d_bt) = cos
        }
    }
    RD_BARRIER();                              // rvs/ras visible to all waves

    // ---- cross term: scale rv_i * ra_j, drop diagonal ----
    // C/D mapping (m74/m101): col = lane&31, row = (reg&3) + 8*(reg>>2) + 4*(lane>>5)
    const float raj = ras[j0 + mrow];
    float od = 0.f;
    #pragma unroll
    for (int r = 0; r < 16; ++r) {
        const int ri = (r & 3) + 8 * (r >> 2) + 4 * half;
        float cc = C[r];
        if (diag && ri == mrow) cc = 0.f;      // i == j diagonal
        od += rvs[i0 + ri] * raj * cc;
    }

    // ---- block reduce + 3 atomics into this block's bin ----
    #pragma unroll
    for (int off = 1; off < 64; off <<= 1) {
        pos += __shfl_xor(pos, off);
        neg += __shfl_xor(neg, off);
        od  += __shfl_xor(od, off);
    }
    if (lane == 0) { wred[0][wave] = pos; wred[1][wave] = neg; wred[2][wave] = od; }
    __syncthreads();
    if (tid == 0) {
        float p = 0.f, n = 0.f, o = 0.f;
        #pragma unroll
        for (int w = 0; w < TPB / 64; ++w) { p += wred[0][w]; n += wred[1][w]; o += wred[2][w]; }
        float* bin = acc + (size_t)(blockIdx.x & (NBIN - 1)) * 4;
        atomicAdd(bin + 0, p);
        atomicAdd(bin + 1, n);
        atomicAdd(bin + 2, o);
    }
}

__global__ void cmfm_final(const int* __restrict__ labels, const float* __restrict__ acc,
                           float* __restrict__ out) {
    const int l = threadIdx.x;     // 64 threads = 64 bins = 64 labels
    float p = acc[l * 4 + 0];
    float n = acc[l * 4 + 1];
    float o = acc[l * 4 + 2];
    float npf = (labels[l] == 0) ? 1.f : 0.f;
    #pragma unroll
    for (int off = 1; off < 64; off <<= 1) {
        p += __shfl_xor(p, off);
        n += __shfl_xor(n, off);
        o += __shfl_xor(o, off);
        npf += __shfl_xor(npf, off);
    }
    if (l == 0) {
        const int np = (int)(npf + 0.5f);
        const float cnt_pos = (float)np * (float)Tn;
        const float cnt_neg = (float)(Bn - np) * (float)Tn + (float)Bn * (float)(Bn - 1);
        float loss = 0.f;
        if (np > 0) loss += 2.0f * p / cnt_pos;                  // ALPHA
        loss += (2.0f * n + 1.0f * o / (float)Tn) / cnt_neg;     // BETA, GAMMA
        out[0] = loss;
    }
}

extern "C" void kernel_launch(void* const* d_in, const int* in_sizes, int n_in,
                              void* d_out, int out_size, void* d_ws, size_t ws_size,
                              hipStream_t stream) {
    const float* fv     = (const float*)d_in[0];
    const float* fa     = (const float*)d_in[1];
    const int*   labels = (const int*)d_in[2];
    float* acc = (float*)d_ws;        // 64 bins x {pos, neg, cross, pad}
    float* out = (float*)d_out;

    hipMemsetAsync(acc, 0, NBIN * 4 * sizeof(float), stream);
    cmfm_main<<<NBLK, TPB, 0, stream>>>(fv, fa, labels, acc);
    cmfm_final<<<1, 64, 0, stream>>>(labels, acc, out);
}